// Round 8
// baseline (392.884 us; speedup 1.0000x reference)
//
#include <hip/hip_runtime.h>
#include <math.h>

typedef __bf16 bf16x8 __attribute__((ext_vector_type(8)));
typedef float  f32x4  __attribute__((ext_vector_type(4)));
typedef float  f32x16 __attribute__((ext_vector_type(16)));

#define MFMA16(a, b, c) __builtin_amdgcn_mfma_f32_16x16x32_bf16((a), (b), (c), 0, 0, 0)
#define MFMA32(a, b, c) __builtin_amdgcn_mfma_f32_32x32x16_bf16((a), (b), (c), 0, 0, 0)

__device__ __forceinline__ unsigned short f2bf(float f) {
    unsigned int u = __float_as_uint(f);
    u += 0x7fffu + ((u >> 16) & 1u);
    return (unsigned short)(u >> 16);
}

// async global->LDS DMA, 16 B per lane (GEMM staging only).
__device__ __forceinline__ void gll16(const unsigned short* g, unsigned short* l) {
    __builtin_amdgcn_global_load_lds(
        (const __attribute__((address_space(1))) unsigned int*)g,
        (__attribute__((address_space(3))) unsigned int*)l, 16, 0, 0);
}

// ---------------------------------------------------------------------------
// Stage 0: fp32 -> bf16 conversion of h and the 4 weight matrices.
// ---------------------------------------------------------------------------
__global__ __launch_bounds__(256) void convert_kernel(
    const float* __restrict__ h, const float* __restrict__ wq,
    const float* __restrict__ wk, const float* __restrict__ wv,
    const float* __restrict__ wo,
    unsigned short* __restrict__ hb, unsigned short* __restrict__ wb)
{
    const int NH4 = 1572864;
    const int NW4 = 147456;
    int i4 = blockIdx.x * 256 + threadIdx.x;
    const float4* src;
    unsigned short* dst;
    int off;
    if (i4 < NH4) {
        src = (const float4*)h; dst = hb; off = i4;
    } else {
        int j = i4 - NH4;
        int w = j / NW4;
        off = j - w * NW4;
        const float* s = (w == 0) ? wq : (w == 1) ? wk : (w == 2) ? wv : wo;
        src = (const float4*)s;
        dst = wb + w * 589824;
    }
    float4 v = src[off];
    ushort4 o;
    o.x = f2bf(v.x); o.y = f2bf(v.y); o.z = f2bf(v.z); o.w = f2bf(v.w);
    ((ushort4*)dst)[off] = o;
}

// ---------------------------------------------------------------------------
// Stage 1/4: C = A @ B^T, double-buffered LDS + single barrier per K-iter.
// (unchanged since R5)
// ---------------------------------------------------------------------------
template <typename OutT>
__global__ __launch_bounds__(256) void gemm_bt(
    const unsigned short* __restrict__ A,
    const unsigned short* __restrict__ Bm,
    OutT* __restrict__ C)
{
    constexpr int K = 768, N = 768;
    __shared__ unsigned short As[2][128 * 32];
    __shared__ unsigned short Bs[2][128 * 32];
    const unsigned short* Bz = Bm + (size_t)blockIdx.z * N * K;
    OutT* Cz = C + (size_t)blockIdx.z * 8192 * N;

    const int tid  = threadIdx.x;
    const int bm   = blockIdx.x * 128, bn = blockIdx.y * 128;
    const int wave = tid >> 6, lane = tid & 63;
    const int wm   = (wave & 1) * 64, wn = (wave >> 1) * 64;
    const int l16  = lane & 15, quad = lane >> 4;

    const int sr  = tid >> 2;
    const int sp8 = ((tid & 3) ^ (sr & 3)) * 8;
    const int slot8 = (quad ^ (l16 & 3)) * 8;

    auto stage = [&](int k0, int bi) {
        gll16(A  + (size_t)(bm + sr) * K      + k0 + sp8, As[bi] + tid * 8);
        gll16(A  + (size_t)(bm + 64 + sr) * K + k0 + sp8, As[bi] + 2048 + tid * 8);
        gll16(Bz + (size_t)(bn + sr) * K      + k0 + sp8, Bs[bi] + tid * 8);
        gll16(Bz + (size_t)(bn + 64 + sr) * K + k0 + sp8, Bs[bi] + 2048 + tid * 8);
    };

    f32x4 acc[4][4] = {};

    stage(0, 0);
    __syncthreads();

    for (int i = 0; i < 24; i++) {
        const int cur = i & 1;
        if (i < 23) stage((i + 1) * 32, cur ^ 1);

        bf16x8 af[4], bfv[4];
        #pragma unroll
        for (int ii = 0; ii < 4; ii++)
            af[ii] = *(const bf16x8*)(As[cur] + (wm + ii * 16 + l16) * 32 + slot8);
        #pragma unroll
        for (int jj = 0; jj < 4; jj++)
            bfv[jj] = *(const bf16x8*)(Bs[cur] + (wn + jj * 16 + l16) * 32 + slot8);
        #pragma unroll
        for (int ii = 0; ii < 4; ii++)
            #pragma unroll
            for (int jj = 0; jj < 4; jj++)
                acc[ii][jj] = MFMA16(af[ii], bfv[jj], acc[ii][jj]);

        __syncthreads();
    }

    #pragma unroll
    for (int ii = 0; ii < 4; ii++) {
        #pragma unroll
        for (int jj = 0; jj < 4; jj++) {
            int row0 = bm + wm + ii * 16 + quad * 4;
            int col  = bn + wn + jj * 16 + l16;
            #pragma unroll
            for (int r = 0; r < 4; r++) {
                float v = acc[ii][jj][r];
                size_t idx = (size_t)(row0 + r) * N + col;
                if constexpr (sizeof(OutT) == 2) Cz[idx] = f2bf(v);
                else                             Cz[idx] = v;
            }
        }
    }
}

// ---------------------------------------------------------------------------
// Stage 2: transpose V per head: [B][24576][64] -> vt[B*12][64][2048].
// ---------------------------------------------------------------------------
__global__ __launch_bounds__(256) void vtrans_kernel(
    const unsigned short* __restrict__ Vg,
    unsigned short* __restrict__ vt)
{
    constexpr int LDT = 72;
    __shared__ unsigned short Ts[64 * LDT];
    const int b = blockIdx.z, hh = blockIdx.y, kp0 = blockIdx.x * 64;
    const int tid = threadIdx.x;
    const size_t boff = (size_t)b * (24576 * 64);
    const int rowV0 = hh * 2048 + kp0;

    #pragma unroll
    for (int rep = 0; rep < 2; rep++) {
        int idx = rep * 256 + tid;
        int r = idx >> 3, dp = (idx & 7) * 8;
        uint4 v = *(const uint4*)(Vg + boff + (size_t)(rowV0 + r) * 64 + dp);
        unsigned short tmp[8];
        *(uint4*)tmp = v;
        #pragma unroll
        for (int i = 0; i < 8; i++) Ts[(dp + i) * LDT + r] = tmp[i];
    }
    __syncthreads();
    unsigned short* vtb = vt + ((size_t)(b * 12 + hh)) * 64 * 2048;
    #pragma unroll
    for (int rep = 0; rep < 2; rep++) {
        int idx = rep * 256 + tid;
        int d = idx >> 3, kp = (idx & 7) * 8;
        uint4 v = *(const uint4*)(Ts + d * LDT + kp);
        *(uint4*)(vtb + (size_t)d * 2048 + kp0 + kp) = v;
    }
}

// ---------------------------------------------------------------------------
// Stage 3: flash attention, round 8: BARRIER-FREE streaming from L2.
//   No LDS staging at all: K, V^T, masks loaded per-fragment directly from
//   global (per-head K/V = 512 KB, L2-resident; c-chunks of a lane cover
//   full 128B lines -> L1 reuse). q-tile 64/block, 4 waves = 2 q-groups x
//   2 k-parities; wave parity p streams tiles kt===p (mod 2) independently
//   (no-max softmax => O,l are order-independent sums). One LDS merge of
//   the two parity partials at the end (16.6 KB, one barrier).
//   Fragment mappings identical to R5 (verified): kf lane(c31,h) chunk c =
//   K[t2*32+c31][c*16+h*8]; qf same on Q rows; vf = V^T[nt*32+c31][kt*64+
//   q*16+h*8]; pf built in-register via lane^32 shuffle; C-layout rows
//   (reg&3)+8*(reg>>2)+4h.
// ---------------------------------------------------------------------------
__global__ __launch_bounds__(256) void attn_kernel(
    const unsigned short* __restrict__ Qg,
    const unsigned short* __restrict__ Kg,
    const unsigned short* __restrict__ vt,   // [B*12][64][2048]
    const int* __restrict__ mask,            // [B][2048]
    unsigned short* __restrict__ Og)         // [B][24576][64]
{
    __shared__ float Ms[2][2][16][64];       // [qg][nt][reg][lane] = 16 KB
    __shared__ float Ls[2][32];              // partial l per q-row

    const int b = blockIdx.z, hh = blockIdx.y, qt = blockIdx.x;   // qt 0..31
    const int tid  = threadIdx.x;
    const int wave = tid >> 6, lane = tid & 63;
    const int qg   = wave >> 1, par = wave & 1;
    const int c31  = lane & 31, h = lane >> 5;
    const size_t boff = (size_t)b * (24576 * 64);
    const int rowQ0 = hh * 2048 + qt * 64;
    const int rowK0 = hh * 2048;
    const unsigned short* vtg = vt + ((size_t)(b * 12 + hh)) * 64 * 2048;

    // Q fragments straight from global (this wave's 32 q-rows)
    const unsigned short* qp = Qg + boff + (size_t)(rowQ0 + qg * 32 + c31) * 64 + h * 8;
    bf16x8 qf[4];
    #pragma unroll
    for (int c = 0; c < 4; c++)
        qf[c] = *(const bf16x8*)(qp + c * 16);

    // per-lane base pointers
    const unsigned short* kbase  = Kg + boff + (size_t)(rowK0 + c31) * 64 + h * 8;
    const unsigned short* vbase0 = vtg + (size_t)c31 * 2048 + h * 8;
    const unsigned short* vbase1 = vtg + (size_t)(32 + c31) * 2048 + h * 8;
    const int* mbase = mask + b * 2048 + 4 * h;

    f32x16 acc[2] = {};
    float l_run = 0.f;
    const float CEXP = 0.18033688011112042f; // 0.125 * log2(e)

    for (int i = 0; i < 16; i++) {
        const int kt = 2 * i + par;

        // S^T[kpos][qrow]: A = K rows (loads near use; occupancy hides latency)
        f32x16 sT[2];
        #pragma unroll
        for (int t2 = 0; t2 < 2; t2++) {
            const unsigned short* kp = kbase + (size_t)(kt * 64 + t2 * 32) * 64;
            f32x16 z = {};
            #pragma unroll
            for (int c = 0; c < 4; c++) {
                bf16x8 kf = *(const bf16x8*)(kp + c * 16);
                z = MFMA32(kf, qf[c], z);
            }
            sT[t2] = z;
        }

        // softmax: e = trunc_bf16(exp2(s*C) * mask); l += e  (R5 numerics)
        unsigned int p01[2][4], p23[2][4];
        #pragma unroll
        for (int t2 = 0; t2 < 2; t2++) {
            #pragma unroll
            for (int s = 0; s < 4; s++) {
                int4 mv = *(const int4*)(mbase + kt * 64 + t2 * 32 + 8 * s);
                float e0 = __builtin_amdgcn_exp2f(sT[t2][4*s+0] * CEXP) * (float)mv.x;
                float e1 = __builtin_amdgcn_exp2f(sT[t2][4*s+1] * CEXP) * (float)mv.y;
                float e2 = __builtin_amdgcn_exp2f(sT[t2][4*s+2] * CEXP) * (float)mv.z;
                float e3 = __builtin_amdgcn_exp2f(sT[t2][4*s+3] * CEXP) * (float)mv.w;
                unsigned int u0 = __float_as_uint(e0) & 0xffff0000u;
                unsigned int u1 = __float_as_uint(e1) & 0xffff0000u;
                unsigned int u2 = __float_as_uint(e2) & 0xffff0000u;
                unsigned int u3 = __float_as_uint(e3) & 0xffff0000u;
                l_run += __uint_as_float(u0) + __uint_as_float(u1)
                       + __uint_as_float(u2) + __uint_as_float(u3);
                p01[t2][s] = __builtin_amdgcn_perm(u1, u0, 0x07060302u);
                p23[t2][s] = __builtin_amdgcn_perm(u3, u2, 0x07060302u);
            }
        }

        // PV: pf built in-register; vf straight from global V^T
        #pragma unroll
        for (int q = 0; q < 4; q++) {
            int t = q >> 1, p = q & 1;
            unsigned int L01 = h ? p01[t][2*p+1] : p01[t][2*p];
            unsigned int L23 = h ? p23[t][2*p+1] : p23[t][2*p];
            unsigned int pre01 = h ? p01[t][2*p] : p01[t][2*p+1];
            unsigned int pre23 = h ? p23[t][2*p] : p23[t][2*p+1];
            unsigned int P01 = (unsigned int)__shfl((int)pre01, lane ^ 32, 64);
            unsigned int P23 = (unsigned int)__shfl((int)pre23, lane ^ 32, 64);
            uint4 pfu;
            pfu.x = h ? P01 : L01;
            pfu.y = h ? P23 : L23;
            pfu.z = h ? L01 : P01;
            pfu.w = h ? L23 : P23;
            bf16x8 pf;
            __builtin_memcpy(&pf, &pfu, 16);
            bf16x8 vf0 = *(const bf16x8*)(vbase0 + kt * 64 + q * 16);
            bf16x8 vf1 = *(const bf16x8*)(vbase1 + kt * 64 + q * 16);
            acc[0] = MFMA32(pf, vf0, acc[0]);
            acc[1] = MFMA32(pf, vf1, acc[1]);
        }
    }

    // fold the two h-halves of l within the wave
    float lt = l_run + __shfl_xor(l_run, 32, 64);

    // merge the two k-parity partials through LDS (one barrier)
    if (par == 1) {
        #pragma unroll
        for (int nt = 0; nt < 2; nt++)
            #pragma unroll
            for (int reg = 0; reg < 16; reg++)
                Ms[qg][nt][reg][lane] = acc[nt][reg];
        if (h == 0) Ls[qg][c31] = lt;
    }
    __syncthreads();
    if (par == 0) {
        #pragma unroll
        for (int nt = 0; nt < 2; nt++)
            #pragma unroll
            for (int reg = 0; reg < 16; reg++)
                acc[nt][reg] += Ms[qg][nt][reg][lane];
        lt += Ls[qg][c31];
        float linv = 1.0f / lt;              // valid on lanes with c31 = q-row
        #pragma unroll
        for (int reg = 0; reg < 16; reg++) {
            int rowfn = (reg & 3) + 8 * (reg >> 2) + 4 * h;
            float li = __shfl(linv, rowfn, 64);
            int row = rowQ0 + qg * 32 + rowfn;
            #pragma unroll
            for (int nt = 0; nt < 2; nt++)
                Og[boff + (size_t)row * 64 + nt * 32 + c31] = f2bf(acc[nt][reg] * li);
        }
    }
}

// ---------------------------------------------------------------------------
extern "C" void kernel_launch(void* const* d_in, const int* in_sizes, int n_in,
                              void* d_out, int out_size, void* d_ws, size_t ws_size,
                              hipStream_t stream)
{
    const float* h    = (const float*)d_in[0];
    const int*   mask = (const int*)d_in[1];
    const float* wq   = (const float*)d_in[2];
    const float* wk   = (const float*)d_in[3];
    const float* wv   = (const float*)d_in[4];
    const float* wo   = (const float*)d_in[5];

    // ws layout (ushorts): hb (reused as V^T) | wb | qkv | ctx = 67.6 MB
    unsigned short* hb  = (unsigned short*)d_ws;
    unsigned short* wb  = hb + 6291456;
    unsigned short* qkv = wb + 4 * 589824;
    unsigned short* ctx = qkv + (size_t)3 * 6291456;

    convert_kernel<<<8448, 256, 0, stream>>>(h, wq, wk, wv, wo, hb, wb);
    gemm_bt<unsigned short><<<dim3(64, 6, 3), 256, 0, stream>>>(hb, wb, qkv);
    // hb is dead now -> reuse as V^T
    vtrans_kernel<<<dim3(32, 12, 4), 256, 0, stream>>>(qkv + (size_t)2 * 6291456, hb);
    attn_kernel<<<dim3(32, 12, 4), 256, 0, stream>>>(
        qkv, qkv + 6291456, hb, mask, ctx);
    gemm_bt<float><<<dim3(64, 6, 1), 256, 0, stream>>>(
        ctx, wb + (size_t)3 * 589824, (float*)d_out);
}

// Round 9
// 257.811 us; speedup vs baseline: 1.5239x; 1.5239x over previous
//
#include <hip/hip_runtime.h>
#include <math.h>

typedef __bf16 bf16x8 __attribute__((ext_vector_type(8)));
typedef float  f32x4  __attribute__((ext_vector_type(4)));
typedef float  f32x16 __attribute__((ext_vector_type(16)));

#define MFMA16(a, b, c) __builtin_amdgcn_mfma_f32_16x16x32_bf16((a), (b), (c), 0, 0, 0)
#define MFMA32(a, b, c) __builtin_amdgcn_mfma_f32_32x32x16_bf16((a), (b), (c), 0, 0, 0)

__device__ __forceinline__ unsigned short f2bf(float f) {
    unsigned int u = __float_as_uint(f);
    u += 0x7fffu + ((u >> 16) & 1u);
    return (unsigned short)(u >> 16);
}

// async global->LDS DMA, 16 B per lane. LDS dest must be wave-uniform base +
// lane*16 (all call sites use lds + tid*8 ushorts).
__device__ __forceinline__ void gll16(const unsigned short* g, unsigned short* l) {
    __builtin_amdgcn_global_load_lds(
        (const __attribute__((address_space(1))) unsigned int*)g,
        (__attribute__((address_space(3))) unsigned int*)l, 16, 0, 0);
}

// ---------------------------------------------------------------------------
// Stage 0: fp32 -> bf16 conversion of h and the 4 weight matrices.
// wq is pre-scaled by 0.125*log2(e) so QK^T emerges in exp2 domain (drops a
// v_mul per score element in the attention softmax).
// ---------------------------------------------------------------------------
__global__ __launch_bounds__(256) void convert_kernel(
    const float* __restrict__ h, const float* __restrict__ wq,
    const float* __restrict__ wk, const float* __restrict__ wv,
    const float* __restrict__ wo,
    unsigned short* __restrict__ hb, unsigned short* __restrict__ wb)
{
    const int NH4 = 1572864;
    const int NW4 = 147456;
    int i4 = blockIdx.x * 256 + threadIdx.x;
    const float4* src;
    unsigned short* dst;
    int off;
    float sc = 1.0f;
    if (i4 < NH4) {
        src = (const float4*)h; dst = hb; off = i4;
    } else {
        int j = i4 - NH4;
        int w = j / NW4;
        off = j - w * NW4;
        const float* s = (w == 0) ? wq : (w == 1) ? wk : (w == 2) ? wv : wo;
        if (w == 0) sc = 0.18033688011112042f;   // 0.125 * log2(e)
        src = (const float4*)s;
        dst = wb + w * 589824;
    }
    float4 v = src[off];
    ushort4 o;
    o.x = f2bf(v.x * sc); o.y = f2bf(v.y * sc);
    o.z = f2bf(v.z * sc); o.w = f2bf(v.w * sc);
    ((ushort4*)dst)[off] = o;
}

// ---------------------------------------------------------------------------
// Stage 1/4: C = A @ B^T, double-buffered LDS + single barrier per K-iter.
// (R5 form, unchanged)
// ---------------------------------------------------------------------------
template <typename OutT>
__global__ __launch_bounds__(256) void gemm_bt(
    const unsigned short* __restrict__ A,
    const unsigned short* __restrict__ Bm,
    OutT* __restrict__ C)
{
    constexpr int K = 768, N = 768;
    __shared__ unsigned short As[2][128 * 32];
    __shared__ unsigned short Bs[2][128 * 32];
    const unsigned short* Bz = Bm + (size_t)blockIdx.z * N * K;
    OutT* Cz = C + (size_t)blockIdx.z * 8192 * N;

    const int tid  = threadIdx.x;
    const int bm   = blockIdx.x * 128, bn = blockIdx.y * 128;
    const int wave = tid >> 6, lane = tid & 63;
    const int wm   = (wave & 1) * 64, wn = (wave >> 1) * 64;
    const int l16  = lane & 15, quad = lane >> 4;

    const int sr  = tid >> 2;
    const int sp8 = ((tid & 3) ^ (sr & 3)) * 8;
    const int slot8 = (quad ^ (l16 & 3)) * 8;

    auto stage = [&](int k0, int bi) {
        gll16(A  + (size_t)(bm + sr) * K      + k0 + sp8, As[bi] + tid * 8);
        gll16(A  + (size_t)(bm + 64 + sr) * K + k0 + sp8, As[bi] + 2048 + tid * 8);
        gll16(Bz + (size_t)(bn + sr) * K      + k0 + sp8, Bs[bi] + tid * 8);
        gll16(Bz + (size_t)(bn + 64 + sr) * K + k0 + sp8, Bs[bi] + 2048 + tid * 8);
    };

    f32x4 acc[4][4] = {};

    stage(0, 0);
    __syncthreads();

    for (int i = 0; i < 24; i++) {
        const int cur = i & 1;
        if (i < 23) stage((i + 1) * 32, cur ^ 1);

        bf16x8 af[4], bfv[4];
        #pragma unroll
        for (int ii = 0; ii < 4; ii++)
            af[ii] = *(const bf16x8*)(As[cur] + (wm + ii * 16 + l16) * 32 + slot8);
        #pragma unroll
        for (int jj = 0; jj < 4; jj++)
            bfv[jj] = *(const bf16x8*)(Bs[cur] + (wn + jj * 16 + l16) * 32 + slot8);
        #pragma unroll
        for (int ii = 0; ii < 4; ii++)
            #pragma unroll
            for (int jj = 0; jj < 4; jj++)
                acc[ii][jj] = MFMA16(af[ii], bfv[jj], acc[ii][jj]);

        __syncthreads();
    }

    #pragma unroll
    for (int ii = 0; ii < 4; ii++) {
        #pragma unroll
        for (int jj = 0; jj < 4; jj++) {
            int row0 = bm + wm + ii * 16 + quad * 4;
            int col  = bn + wn + jj * 16 + l16;
            #pragma unroll
            for (int r = 0; r < 4; r++) {
                float v = acc[ii][jj][r];
                size_t idx = (size_t)(row0 + r) * N + col;
                if constexpr (sizeof(OutT) == 2) Cz[idx] = f2bf(v);
                else                             Cz[idx] = v;
            }
        }
    }
}

// ---------------------------------------------------------------------------
// Stage 2: transpose V per head: [B][24576][64] -> vt[B*12][64][2048].
// ---------------------------------------------------------------------------
__global__ __launch_bounds__(256) void vtrans_kernel(
    const unsigned short* __restrict__ Vg,
    unsigned short* __restrict__ vt)
{
    constexpr int LDT = 72;
    __shared__ unsigned short Ts[64 * LDT];
    const int b = blockIdx.z, hh = blockIdx.y, kp0 = blockIdx.x * 64;
    const int tid = threadIdx.x;
    const size_t boff = (size_t)b * (24576 * 64);
    const int rowV0 = hh * 2048 + kp0;

    #pragma unroll
    for (int rep = 0; rep < 2; rep++) {
        int idx = rep * 256 + tid;
        int r = idx >> 3, dp = (idx & 7) * 8;
        uint4 v = *(const uint4*)(Vg + boff + (size_t)(rowV0 + r) * 64 + dp);
        unsigned short tmp[8];
        *(uint4*)tmp = v;
        #pragma unroll
        for (int i = 0; i < 8; i++) Ts[(dp + i) * LDT + r] = tmp[i];
    }
    __syncthreads();
    unsigned short* vtb = vt + ((size_t)(b * 12 + hh)) * 64 * 2048;
    #pragma unroll
    for (int rep = 0; rep < 2; rep++) {
        int idx = rep * 256 + tid;
        int d = idx >> 3, kp = (idx & 7) * 8;
        uint4 v = *(const uint4*)(Ts + d * LDT + kp);
        *(uint4*)(vtb + (size_t)d * 2048 + kp0 + kp) = v;
    }
}

// ---------------------------------------------------------------------------
// Stage 3: flash attention = R5 structure (LDS dbuf, 1 barrier/tile, S^T
// trick, in-register P) + R9 changes:
//   (1) mask never touches the vmcnt queue in the hot loop: a 256 B per-tile
//       bitmap (msh, LDS) is built once in the prologue from coalesced int4
//       reads; per tile one broadcast ds_read_b64 + uniform branch. All-ones
//       tiles (the bench case) run a softmax with ZERO mask ops; general
//       tiles take a cndmask path. R5's in-tile int4 mask loads sat behind
//       the staging DMAs in the vmcnt queue and forced a mid-tile drain
//       every tile (R6/R7 post-mortems) — this removes that stall without
//       R7's ping-pong VGPR cost.
//   (2) wq pre-scaled by 0.125*log2(e) -> sT is already in exp2 domain.
// ---------------------------------------------------------------------------
__global__ __launch_bounds__(256) void attn_kernel(
    const unsigned short* __restrict__ Qg,
    const unsigned short* __restrict__ Kg,
    const unsigned short* __restrict__ vt,   // [B*12][64][2048]
    const int* __restrict__ mask,            // [B][2048]
    unsigned short* __restrict__ Og)         // [B][24576][64]
{
    __shared__ unsigned short Qs[128 * 64];
    __shared__ unsigned short Ks[2][64 * 64];
    __shared__ unsigned short Vs[2][64 * 64];
    __shared__ unsigned long long msh[32];   // per-k-tile mask bitmap (64 bits)

    const int b = blockIdx.z, hh = blockIdx.y, qt = blockIdx.x;
    const int tid  = threadIdx.x;
    const int wave = tid >> 6, lane = tid & 63;
    const int c31  = lane & 31, h = lane >> 5;
    const size_t boff = (size_t)b * (24576 * 64);
    const int rowQ0 = hh * 2048 + qt * 128;
    const int rowK0 = hh * 2048;
    const unsigned short* vtg = vt + ((size_t)(b * 12 + hh)) * 64 * 2048;
    const int sw = c31 & 7;                  // read-side swizzle

    // staging map (shared by Q/K/V): row = i*32 + tid>>3, chunk ^= row&7
    const int srow = tid >> 3;
    const int sch8 = ((tid & 7) ^ (srow & 7)) * 8;

    auto stageKV = [&](int kt, int bi) {
        #pragma unroll
        for (int i = 0; i < 2; i++) {
            int row = i * 32 + srow;
            gll16(Kg  + boff + (size_t)(rowK0 + kt * 64 + row) * 64 + sch8,
                  Ks[bi] + i * 2048 + tid * 8);
            gll16(vtg + (size_t)row * 2048 + kt * 64 + sch8,
                  Vs[bi] + i * 2048 + tid * 8);
        }
    };

    // stage Q tile [128][64] (fetch-swizzled) + K/V tile 0
    #pragma unroll
    for (int i = 0; i < 4; i++) {
        int row = i * 32 + srow;
        gll16(Qg + boff + (size_t)(rowQ0 + row) * 64 + sch8, Qs + i * 2048 + tid * 8);
    }
    stageKV(0, 0);

    // build mask bitmap: thread t covers k-positions [t*8, t*8+8)
    {
        const int4 a = *(const int4*)(mask + b * 2048 + tid * 8);
        const int4 c = *(const int4*)(mask + b * 2048 + tid * 8 + 4);
        unsigned char byte =
            (a.x != 0 ? 1u : 0u)       | (a.y != 0 ? 2u : 0u) |
            (a.z != 0 ? 4u : 0u)       | (a.w != 0 ? 8u : 0u) |
            (c.x != 0 ? 16u : 0u)      | (c.y != 0 ? 32u : 0u) |
            (c.z != 0 ? 64u : 0u)      | (c.w != 0 ? 128u : 0u);
        ((unsigned char*)msh)[tid] = byte;
    }
    __syncthreads();

    bf16x8 qf[4];                            // B-operand: n=c31 (q-row), k=c*16+8h+j
    #pragma unroll
    for (int c = 0; c < 4; c++) {
        int ch = (2 * c + h) ^ sw;
        qf[c] = *(const bf16x8*)(Qs + (wave * 32 + c31) * 64 + ch * 8);
    }

    f32x16 acc[2] = {};                      // O: row=q-row fn(reg,h), col=d=nt*32+c31
    float l_run = 0.f;                       // for q-row = wave*32 + c31

    for (int kt = 0; kt < 32; kt++) {
        const int cur = kt & 1;
        if (kt < 31) stageKV(kt + 1, cur ^ 1);   // prefetch next K/V tile

        const unsigned long long am = msh[kt];   // broadcast ds_read_b64

        // S^T[kpos][qrow]: A = K rows (m=kpos), B = Q rows (n=qrow)
        f32x16 sT[2];
        #pragma unroll
        for (int t2 = 0; t2 < 2; t2++) {
            f32x16 z = {};
            #pragma unroll
            for (int c = 0; c < 4; c++) {
                int ch = (2 * c + h) ^ sw;
                bf16x8 kf = *(const bf16x8*)(Ks[cur] + (t2 * 32 + c31) * 64 + ch * 8);
                z = MFMA32(kf, qf[c], z);
            }
            sT[t2] = z;
        }

        // softmax: e = trunc_bf16(exp2(sT)); l += e_trunc  (R5 numerics,
        // scale pre-folded into wq). Uniform branch on the mask bitmap.
        unsigned int p01[2][4], p23[2][4];
        if (am == ~0ull) {
            #pragma unroll
            for (int t2 = 0; t2 < 2; t2++) {
                #pragma unroll
                for (int s = 0; s < 4; s++) {
                    float e0 = __builtin_amdgcn_exp2f(sT[t2][4*s+0]);
                    float e1 = __builtin_amdgcn_exp2f(sT[t2][4*s+1]);
                    float e2 = __builtin_amdgcn_exp2f(sT[t2][4*s+2]);
                    float e3 = __builtin_amdgcn_exp2f(sT[t2][4*s+3]);
                    unsigned int u0 = __float_as_uint(e0) & 0xffff0000u;
                    unsigned int u1 = __float_as_uint(e1) & 0xffff0000u;
                    unsigned int u2 = __float_as_uint(e2) & 0xffff0000u;
                    unsigned int u3 = __float_as_uint(e3) & 0xffff0000u;
                    l_run += __uint_as_float(u0) + __uint_as_float(u1)
                           + __uint_as_float(u2) + __uint_as_float(u3);
                    p01[t2][s] = __builtin_amdgcn_perm(u1, u0, 0x07060302u);
                    p23[t2][s] = __builtin_amdgcn_perm(u3, u2, 0x07060302u);
                }
            }
        } else {
            #pragma unroll
            for (int t2 = 0; t2 < 2; t2++) {
                #pragma unroll
                for (int s = 0; s < 4; s++) {
                    unsigned int nib = (unsigned int)(am >> (t2 * 32 + 8 * s + 4 * h)) & 0xFu;
                    float e0 = __builtin_amdgcn_exp2f(sT[t2][4*s+0]);
                    float e1 = __builtin_amdgcn_exp2f(sT[t2][4*s+1]);
                    float e2 = __builtin_amdgcn_exp2f(sT[t2][4*s+2]);
                    float e3 = __builtin_amdgcn_exp2f(sT[t2][4*s+3]);
                    e0 = (nib & 1u) ? e0 : 0.f;
                    e1 = (nib & 2u) ? e1 : 0.f;
                    e2 = (nib & 4u) ? e2 : 0.f;
                    e3 = (nib & 8u) ? e3 : 0.f;
                    unsigned int u0 = __float_as_uint(e0) & 0xffff0000u;
                    unsigned int u1 = __float_as_uint(e1) & 0xffff0000u;
                    unsigned int u2 = __float_as_uint(e2) & 0xffff0000u;
                    unsigned int u3 = __float_as_uint(e3) & 0xffff0000u;
                    l_run += __uint_as_float(u0) + __uint_as_float(u1)
                           + __uint_as_float(u2) + __uint_as_float(u3);
                    p01[t2][s] = __builtin_amdgcn_perm(u1, u0, 0x07060302u);
                    p23[t2][s] = __builtin_amdgcn_perm(u3, u2, 0x07060302u);
                }
            }
        }

        // PV: build A-frags (m=qrow=c31, k=q*16+8h+j) from sT values in-register
        #pragma unroll
        for (int q = 0; q < 4; q++) {
            int t = q >> 1, p = q & 1;
            unsigned int L01 = h ? p01[t][2*p+1] : p01[t][2*p];
            unsigned int L23 = h ? p23[t][2*p+1] : p23[t][2*p];
            unsigned int pre01 = h ? p01[t][2*p] : p01[t][2*p+1];
            unsigned int pre23 = h ? p23[t][2*p] : p23[t][2*p+1];
            unsigned int P01 = (unsigned int)__shfl((int)pre01, lane ^ 32, 64);
            unsigned int P23 = (unsigned int)__shfl((int)pre23, lane ^ 32, 64);
            uint4 pfu;
            pfu.x = h ? P01 : L01;
            pfu.y = h ? P23 : L23;
            pfu.z = h ? L01 : P01;
            pfu.w = h ? L23 : P23;
            bf16x8 pf;
            __builtin_memcpy(&pf, &pfu, 16);
            #pragma unroll
            for (int nt = 0; nt < 2; nt++) {
                int ch = (2 * q + h) ^ sw;
                bf16x8 vf = *(const bf16x8*)(Vs[cur] + (nt * 32 + c31) * 64 + ch * 8);
                acc[nt] = MFMA32(pf, vf, acc[nt]);
            }
        }

        __syncthreads();                     // reads of cur done + next DMA drained
    }

    // epilogue: combine the two half-l's per q-row, then O/l
    float lt = l_run + __shfl_xor(l_run, 32, 64);
    float linv = 1.0f / lt;                  // for q-row = wave*32 + c31
    #pragma unroll
    for (int reg = 0; reg < 16; reg++) {
        int rowfn = (reg & 3) + 8 * (reg >> 2) + 4 * h;
        float li = __shfl(linv, rowfn, 64);
        int row = rowQ0 + wave * 32 + rowfn;
        #pragma unroll
        for (int nt = 0; nt < 2; nt++)
            Og[boff + (size_t)row * 64 + nt * 32 + c31] = f2bf(acc[nt][reg] * li);
    }
}

// ---------------------------------------------------------------------------
extern "C" void kernel_launch(void* const* d_in, const int* in_sizes, int n_in,
                              void* d_out, int out_size, void* d_ws, size_t ws_size,
                              hipStream_t stream)
{
    const float* h    = (const float*)d_in[0];
    const int*   mask = (const int*)d_in[1];
    const float* wq   = (const float*)d_in[2];
    const float* wk   = (const float*)d_in[3];
    const float* wv   = (const float*)d_in[4];
    const float* wo   = (const float*)d_in[5];

    // ws layout (ushorts): hb (reused as V^T) | wb | qkv | ctx = 67.6 MB
    unsigned short* hb  = (unsigned short*)d_ws;
    unsigned short* wb  = hb + 6291456;
    unsigned short* qkv = wb + 4 * 589824;
    unsigned short* ctx = qkv + (size_t)3 * 6291456;

    convert_kernel<<<8448, 256, 0, stream>>>(h, wq, wk, wv, wo, hb, wb);
    gemm_bt<unsigned short><<<dim3(64, 6, 3), 256, 0, stream>>>(hb, wb, qkv);
    // hb is dead now -> reuse as V^T
    vtrans_kernel<<<dim3(32, 12, 4), 256, 0, stream>>>(qkv + (size_t)2 * 6291456, hb);
    attn_kernel<<<dim3(16, 12, 4), 256, 0, stream>>>(
        qkv, qkv + 6291456, hb, mask, ctx);
    gemm_bt<float><<<dim3(64, 6, 1), 256, 0, stream>>>(
        ctx, wb + (size_t)3 * 589824, (float*)d_out);
}